// Round 7
// baseline (660.483 us; speedup 1.0000x reference)
//
#include <hip/hip_runtime.h>
#include <hip/hip_cooperative_groups.h>

namespace cg = cooperative_groups;

typedef unsigned short u16;
typedef __attribute__((ext_vector_type(8))) short short8;
typedef __attribute__((ext_vector_type(4))) float f32x4;

__device__ __forceinline__ float bflo(unsigned u) {
    union { unsigned u; float f; } v; v.u = u << 16; return v.f;
}
__device__ __forceinline__ float bfhi(unsigned u) {
    union { unsigned u; float f; } v; v.u = u & 0xFFFF0000u; return v.f;
}
__device__ __forceinline__ float bf2f(u16 h) {
    union { unsigned u; float f; } v; v.u = ((unsigned)h) << 16; return v.f;
}
__device__ __forceinline__ u16 f2bf(float f) {
    union { float f; unsigned u; } v; v.f = f;
    unsigned u = v.u;
    u += 0x7FFFu + ((u >> 16) & 1u);   // round-to-nearest-even
    return (u16)(u >> 16);
}

// ---- GEMM phase (device): out = (A @ W) * dinv[:,None], bf16 MFMA ---------
// Requires M % 16 == 0 (N=50000 ok). W staged once per block into LDS.
template <int NOUT>
__device__ void gemm_phase(const void* __restrict__ Av, const u16* __restrict__ W,
                           const float* __restrict__ dinv, u16* __restrict__ outp,
                           int M, int useF32, char* lds_) {
    u16 (*Wt)[136] = (u16(*)[136])lds_;
    int t = threadIdx.x;
    __syncthreads();                         // LDS handoff from previous phase
    for (int idx = t; idx < NOUT * 128; idx += 256) {
        int k = idx / NOUT, n = idx % NOUT;  // W row-major [128][NOUT]
        Wt[n][k] = W[idx];
    }
    __syncthreads();
    int wave = t >> 6, lane = t & 63;
    int q = lane >> 4;
    int mr = lane & 15;
    int wt0 = blockIdx.x * 4 + wave;
    int nwt = gridDim.x * 4;
    int tiles = M / 16;

    for (int wt = wt0; wt < tiles; wt += nwt) {
        int m0 = wt * 16;
        short8 a[4];
        if (useF32) {
            const float* arow = (const float*)Av + (size_t)(m0 + mr) * 128 + q * 8;
#pragma unroll
            for (int c = 0; c < 4; c++) {
                f32x4 lo = *(const f32x4*)(arow + c * 32);
                f32x4 hi = *(const f32x4*)(arow + c * 32 + 4);
                a[c][0] = (short)f2bf(lo.x); a[c][1] = (short)f2bf(lo.y);
                a[c][2] = (short)f2bf(lo.z); a[c][3] = (short)f2bf(lo.w);
                a[c][4] = (short)f2bf(hi.x); a[c][5] = (short)f2bf(hi.y);
                a[c][6] = (short)f2bf(hi.z); a[c][7] = (short)f2bf(hi.w);
            }
        } else {
            const u16* arow = (const u16*)Av + (size_t)(m0 + mr) * 128 + q * 8;
#pragma unroll
            for (int c = 0; c < 4; c++) a[c] = *(const short8*)(arow + c * 32);
        }

        f32x4 acc[NOUT / 16];
#pragma unroll
        for (int tl = 0; tl < NOUT / 16; tl++) acc[tl] = (f32x4){0.f, 0.f, 0.f, 0.f};
#pragma unroll
        for (int c = 0; c < 4; c++) {
#pragma unroll
            for (int tl = 0; tl < NOUT / 16; tl++) {
                short8 b = *(const short8*)(&Wt[tl * 16 + mr][c * 32 + q * 8]);
                acc[tl] = __builtin_amdgcn_mfma_f32_16x16x32_bf16(a[c], b, acc[tl], 0, 0, 0);
            }
        }
        int rbase = m0 + q * 4;   // C/D: col=lane&15, row=(lane>>4)*4+reg
#pragma unroll
        for (int tl = 0; tl < NOUT / 16; tl++) {
#pragma unroll
            for (int r = 0; r < 4; r++) {
                int row = rbase + r;
                float v = acc[tl][r] * dinv[row];
                outp[(size_t)row * NOUT + tl * 16 + mr] = f2bf(v);
            }
        }
    }
}

// ---- aggregation phase (device): round-5/6 passing k_agg body, wave-per-node
template <int F>
__device__ void agg_phase(const u16* __restrict__ g, const int* __restrict__ rowp,
                          const int* __restrict__ col, const float* __restrict__ dinv,
                          const u16* __restrict__ bias, u16* __restrict__ outh,
                          float* __restrict__ outf, int useF32, int N, int E) {
    constexpr int LPR = F / 8;
    constexpr int EPW = 64 / LPR;
    int lane = threadIdx.x & 63;
    int er = lane / LPR;
    int fo = (lane % LPR) * 8;
    int wid = blockIdx.x * 4 + (threadIdx.x >> 6);
    int nw = gridDim.x * 4;

    for (int d = wid; d < N; d += nw) {
        int beg = rowp[d], end = rowp[d + 1];
        if (beg < 0) beg = 0;
        if (end > E) end = E;
        int deg = end - beg;

        float a0[8], a1[8];
#pragma unroll
        for (int j = 0; j < 8; j++) { a0[j] = 0.f; a1[j] = 0.f; }

        for (int base = 0; base < deg; base += 64) {
            int cnt = deg - base; if (cnt > 64) cnt = 64;
            int colv = 0;
            if (lane < cnt) {
                int s = col[beg + base + lane];
                colv = s < 0 ? 0 : (s >= N ? N - 1 : s);
            }
            int full = cnt / EPW;
            int i = 0;
            for (; i + 2 <= full; i += 2) {
                int s0 = __shfl(colv, i * EPW + er, 64);
                int s1 = __shfl(colv, (i + 1) * EPW + er, 64);
                uint4 v0 = *(const uint4*)(g + (size_t)s0 * F + fo);
                uint4 v1 = *(const uint4*)(g + (size_t)s1 * F + fo);
                a0[0] += bflo(v0.x); a0[1] += bfhi(v0.x);
                a0[2] += bflo(v0.y); a0[3] += bfhi(v0.y);
                a0[4] += bflo(v0.z); a0[5] += bfhi(v0.z);
                a0[6] += bflo(v0.w); a0[7] += bfhi(v0.w);
                a1[0] += bflo(v1.x); a1[1] += bfhi(v1.x);
                a1[2] += bflo(v1.y); a1[3] += bfhi(v1.y);
                a1[4] += bflo(v1.z); a1[5] += bfhi(v1.z);
                a1[6] += bflo(v1.w); a1[7] += bfhi(v1.w);
            }
            if (i < full) {
                int s0 = __shfl(colv, i * EPW + er, 64);
                uint4 v0 = *(const uint4*)(g + (size_t)s0 * F + fo);
                a0[0] += bflo(v0.x); a0[1] += bfhi(v0.x);
                a0[2] += bflo(v0.y); a0[3] += bfhi(v0.y);
                a0[4] += bflo(v0.z); a0[5] += bfhi(v0.z);
                a0[6] += bflo(v0.w); a0[7] += bfhi(v0.w);
                i++;
            }
            int rem = cnt - full * EPW;
            int s0 = __shfl(colv, (full * EPW + er) & 63, 64);
            if (er < rem) {
                uint4 v0 = *(const uint4*)(g + (size_t)s0 * F + fo);
                a0[0] += bflo(v0.x); a0[1] += bfhi(v0.x);
                a0[2] += bflo(v0.y); a0[3] += bfhi(v0.y);
                a0[4] += bflo(v0.z); a0[5] += bfhi(v0.z);
                a0[6] += bflo(v0.w); a0[7] += bfhi(v0.w);
            }
        }
#pragma unroll
        for (int j = 0; j < 8; j++) a0[j] += a1[j];
#pragma unroll
        for (int off = LPR; off < 64; off <<= 1) {
#pragma unroll
            for (int j = 0; j < 8; j++) a0[j] += __shfl_xor(a0[j], off, 64);
        }

        if (lane < LPR) {
            uint4 sv = *(const uint4*)(g + (size_t)d * F + fo);
            uint4 bv = *(const uint4*)(bias + fo);
            float di = dinv[d];
            float r[8];
            r[0] = di * (a0[0] + bflo(sv.x)) + bflo(bv.x);
            r[1] = di * (a0[1] + bfhi(sv.x)) + bfhi(bv.x);
            r[2] = di * (a0[2] + bflo(sv.y)) + bflo(bv.y);
            r[3] = di * (a0[3] + bfhi(sv.y)) + bfhi(bv.y);
            r[4] = di * (a0[4] + bflo(sv.z)) + bflo(bv.z);
            r[5] = di * (a0[5] + bfhi(sv.z)) + bfhi(bv.z);
            r[6] = di * (a0[6] + bflo(sv.w)) + bflo(bv.w);
            r[7] = di * (a0[7] + bfhi(sv.w)) + bfhi(bv.w);
#pragma unroll
            for (int j = 0; j < 8; j++) r[j] = r[j] > 0.f ? r[j] : 0.f;
            size_t o = (size_t)d * F + fo;
            if (useF32) {
                f32x4 w0 = {r[0], r[1], r[2], r[3]};
                f32x4 w1 = {r[4], r[5], r[6], r[7]};
                *(f32x4*)(outf + o) = w0;
                *(f32x4*)(outf + o + 4) = w1;
            } else {
                uint4 w;
                w.x = (unsigned)f2bf(r[0]) | ((unsigned)f2bf(r[1]) << 16);
                w.y = (unsigned)f2bf(r[2]) | ((unsigned)f2bf(r[3]) << 16);
                w.z = (unsigned)f2bf(r[4]) | ((unsigned)f2bf(r[5]) << 16);
                w.w = (unsigned)f2bf(r[6]) | ((unsigned)f2bf(r[7]) << 16);
                *(uint4*)(outh + o) = w;
            }
        }
    }
}

// ---- the single cooperative mega-kernel -----------------------------------
// Phases separated by grid.sync(); all control flow funnels through the syncs
// (no early returns). Assumes N <= 65536 (scan-top fits one 256-wide tile).

__global__ __launch_bounds__(256, 4) void k_mega(
    const void* __restrict__ x, const int* __restrict__ src,
    const int* __restrict__ dst,
    const void* __restrict__ W1, const void* __restrict__ b1,
    const void* __restrict__ W2, const void* __restrict__ b2,
    void* __restrict__ out, int N, int E,
    int* __restrict__ flagcnt, int* __restrict__ rowp,
    float* __restrict__ dinv, int* __restrict__ col,
    u16* __restrict__ wbuf, char* __restrict__ slotA, char* __restrict__ slotB) {

    __shared__ char lds_[128 * 136 * 2];   // 34816 B, aliased per phase
    cg::grid_group grid = cg::this_grid();
    int tid = threadIdx.x;
    int bid = blockIdx.x;
    int nb_ = gridDim.x;
    int gtid = bid * 256 + tid;
    int gsz = nb_ * 256;

    int* cnt  = (int*)slotA;                    // dead after P2
    int* sums = (int*)(slotA + (size_t)N * 4);  // dead after P2
    u16* g1   = (u16*)slotA;                    // written P3
    u16* g2   = (u16*)slotA;                    // written P5
    int* pos  = (int*)slotB;                    // dead after P3
    u16* o1   = (u16*)slotB;                    // written P4
    u16* W1C = wbuf;
    u16* b1C = wbuf + 128 * 128;
    u16* W2C = b1C + 128;
    u16* b2C = W2C + 128 * 64;

    // ---- P0: dtype-detect sampling + degree histogram w/ per-edge slot ----
    {
        int c = 0;
        for (int i = gtid; i < 2048; i += gsz) {
            int e = (((const u16*)x)[2 * i] >> 7) & 0xFF;
            c += (e >= 160 || e <= 80) ? 1 : 0;
        }
        if (c) atomicAdd(flagcnt, c);
        for (int e = gtid; e < E; e += gsz)
            pos[e] = atomicAdd(&cnt[dst[e]], 1);
    }
    grid.sync();
    int flag = (*(volatile int*)flagcnt > 64) ? 1 : 0;

    // ---- P1: weight canonicalization + per-tile exclusive scan of cnt ----
    {
        const int n1 = 128 * 128, n2 = n1 + 128, n3 = n2 + 128 * 64, n4 = n3 + 64;
        for (int i = gtid; i < n4; i += gsz) {
            const void* sp; int off;
            if (i < n1)      { sp = W1; off = i; }
            else if (i < n2) { sp = b1; off = i - n1; }
            else if (i < n3) { sp = W2; off = i - n2; }
            else             { sp = b2; off = i - n3; }
            wbuf[i] = flag ? f2bf(((const float*)sp)[off]) : ((const u16*)sp)[off];
        }
        int ntile = (N + 255) / 256;
        int* s = (int*)lds_;
        for (int t = bid; t < ntile; t += nb_) {
            int i = t * 256 + tid;
            int v = (i < N) ? cnt[i] : 0;
            __syncthreads();                  // protect LDS across iterations
            s[tid] = v;
            __syncthreads();
            for (int off = 1; off < 256; off <<= 1) {
                int add = (tid >= off) ? s[tid - off] : 0;
                __syncthreads();
                s[tid] += add;
                __syncthreads();
            }
            if (i < N) rowp[i] = s[tid] - v;  // block-local exclusive
            if (tid == 255) sums[t] = s[255];
        }
    }
    grid.sync();

    // ---- P2: scan of tile sums (each block redundantly) + finalize --------
    {
        int ntile = (N + 255) / 256;
        int* s = (int*)lds_;
        __syncthreads();
        int v = (tid < ntile) ? sums[tid] : 0;   // sums[ntile..255] zeroed by memset
        s[tid] = v;
        __syncthreads();
        for (int off = 1; off < 256; off <<= 1) {
            int add = (tid >= off) ? s[tid - off] : 0;
            __syncthreads();
            s[tid] += add;
            __syncthreads();
        }
        for (int t = bid; t < ntile; t += nb_) {
            int prefix = (t == 0) ? 0 : s[t - 1];
            int i = t * 256 + tid;
            if (i < N) {
                rowp[i] += prefix;
                dinv[i] = rsqrtf((float)cnt[i] + 1.0f);   // deg incl. self-loop
            }
        }
        if (gtid == 0) rowp[N] = E;
    }
    grid.sync();

    // ---- P3: gemm1 (x @ W1)*dinv -> g1   ||   atomic-free CSR fill --------
    gemm_phase<128>(x, W1C, dinv, g1, N, flag, lds_);
    for (int e = gtid; e < E; e += gsz)
        col[rowp[dst[e]] + pos[e]] = src[e];
    grid.sync();

    // ---- P4: aggregate layer 1 -> o1 (bf16) -------------------------------
    agg_phase<128>(g1, rowp, col, dinv, b1C, o1, nullptr, 0, N, E);
    grid.sync();

    // ---- P5: gemm2 (o1 @ W2)*dinv -> g2 -----------------------------------
    gemm_phase<64>(o1, W2C, dinv, g2, N, 0, lds_);
    grid.sync();

    // ---- P6: aggregate layer 2 -> out -------------------------------------
    agg_phase<64>(g2, rowp, col, dinv, b2C, (u16*)out, (float*)out, flag, N, E);
}

// ---- launch ---------------------------------------------------------------

extern "C" void kernel_launch(void* const* d_in, const int* in_sizes, int n_in,
                              void* d_out, int out_size, void* d_ws, size_t ws_size,
                              hipStream_t stream) {
    int N = in_sizes[0] / 128;
    int E = in_sizes[1] / 2;
    const void* x  = d_in[0];
    const int* ei  = (const int*)d_in[1];
    const int* src = ei;
    const int* dst = ei + E;
    const void* W1 = d_in[2];
    const void* b1 = d_in[3];
    const void* W2 = d_in[4];
    const void* b2 = d_in[5];
    void* out = d_out;

    char* p = (char*)d_ws;
    auto alloc = [&](size_t b) { char* r = p; p += (b + 255) & ~(size_t)255; return r; };
    int*   flagcnt = (int*)alloc(256);
    int*   rowp = (int*)alloc((size_t)(N + 1) * 4);
    float* dinv = (float*)alloc((size_t)N * 4);
    int*   col  = (int*)alloc((size_t)E * 4);
    u16*   wbuf = (u16*)alloc((size_t)(128 * 128 + 128 + 128 * 64 + 64) * 2);
    char*  slotA = alloc((size_t)N * 128 * 2);   // cnt+sums early; g1; g2
    char*  slotB = alloc((size_t)N * 128 * 2);   // pos early; o1 later

    hipMemsetAsync(flagcnt, 0, 256, stream);
    hipMemsetAsync(slotA, 0, (size_t)N * 4 + 1024, stream);   // cnt + sums

    // co-resident grid: occupancy-query, clamped to [1,4] blocks/CU
    int bpc = 0;
    if (hipOccupancyMaxActiveBlocksPerMultiprocessor(&bpc, k_mega, 256, 0)
            != hipSuccess || bpc < 1) bpc = 2;
    if (bpc > 4) bpc = 4;
    int grid = 256 * bpc;

    void* args[] = { (void*)&x, (void*)&src, (void*)&dst,
                     (void*)&W1, (void*)&b1, (void*)&W2, (void*)&b2,
                     (void*)&out, (void*)&N, (void*)&E,
                     (void*)&flagcnt, (void*)&rowp, (void*)&dinv, (void*)&col,
                     (void*)&wbuf, (void*)&slotA, (void*)&slotB };
    hipLaunchCooperativeKernel((void*)k_mega, dim3(grid), dim3(256),
                               args, 0, stream);
}

// Round 9
// 214.282 us; speedup vs baseline: 3.0823x; 3.0823x over previous
//
#include <hip/hip_runtime.h>

typedef unsigned short u16;
typedef __attribute__((ext_vector_type(8))) short short8;
typedef __attribute__((ext_vector_type(4))) float f32x4;

__device__ __forceinline__ float bflo(unsigned u) {
    union { unsigned u; float f; } v; v.u = u << 16; return v.f;
}
__device__ __forceinline__ float bfhi(unsigned u) {
    union { unsigned u; float f; } v; v.u = u & 0xFFFF0000u; return v.f;
}
__device__ __forceinline__ float bf2f(u16 h) {
    union { unsigned u; float f; } v; v.u = ((unsigned)h) << 16; return v.f;
}
__device__ __forceinline__ u16 f2bf(float f) {
    union { float f; unsigned u; } v; v.f = f;
    unsigned u = v.u;
    u += 0x7FFFu + ((u >> 16) & 1u);   // round-to-nearest-even
    return (u16)(u >> 16);
}

// ---- dtype detection ------------------------------------------------------
// All observed runs are float32 (flag=1): rounds 1/8 read bf16 directly and
// failed identically at 1.33e36; flag-path rounds passed. Kept as cheap
// insurance for both dtypes.
__global__ void k_detect(const u16* __restrict__ x, int* __restrict__ flag) {
    __shared__ int c_s;
    if (threadIdx.x == 0) c_s = 0;
    __syncthreads();
    int c = 0;
    for (int i = threadIdx.x; i < 2048; i += blockDim.x) {
        int e = (x[2 * i] >> 7) & 0xFF;
        c += (e >= 160 || e <= 80) ? 1 : 0;
    }
    atomicAdd(&c_s, c);
    __syncthreads();
    if (threadIdx.x == 0) *flag = (c_s > 64) ? 1 : 0;
}

// all four weight/bias arrays canonicalized to bf16 in one launch
__global__ void k_convert_w(const void* __restrict__ W1, const void* __restrict__ b1,
                            const void* __restrict__ W2, const void* __restrict__ b2,
                            u16* __restrict__ out, const int* __restrict__ flag) {
    const int n1 = 128 * 128, n2 = n1 + 128, n3 = n2 + 128 * 64, n4 = n3 + 64;
    int i = blockIdx.x * 256 + threadIdx.x;
    if (i >= n4) return;
    const void* src; int off;
    if (i < n1)      { src = W1; off = i; }
    else if (i < n2) { src = b1; off = i - n1; }
    else if (i < n3) { src = W2; off = i - n2; }
    else             { src = b2; off = i - n3; }
    out[i] = *flag ? f2bf(((const float*)src)[off]) : ((const u16*)src)[off];
}

// ---- CSR build ------------------------------------------------------------
// Pass 1: degree histogram AND per-edge slot in one atomic.

__global__ void k_degpos(const int* __restrict__ dst, int* __restrict__ cnt,
                         int* __restrict__ pos, int E) {
    int e = blockIdx.x * blockDim.x + threadIdx.x;
    if (e < E) pos[e] = atomicAdd(&cnt[dst[e]], 1);
}

__global__ void k_scan_blocks(const int* __restrict__ cnt, int* __restrict__ rowp,
                              int* __restrict__ sums, int n) {
    __shared__ int s[256];
    int t = threadIdx.x;
    int i = blockIdx.x * 256 + t;
    int v = (i < n) ? cnt[i] : 0;
    s[t] = v;
    __syncthreads();
    for (int off = 1; off < 256; off <<= 1) {
        int add = (t >= off) ? s[t - off] : 0;
        __syncthreads();
        s[t] += add;
        __syncthreads();
    }
    if (i < n) rowp[i] = s[t] - v;
    if (t == 255) sums[blockIdx.x] = s[255];
}

// Merged top-scan + finalize: every block redundantly scans the <=256 tile
// sums (sums[ntile..255] zeroed by host memset), applies its tile's prefix,
// and computes dinv. Assumes N <= 65536.
__global__ void k_finalize2(int* __restrict__ rowp, const int* __restrict__ sums,
                            const int* __restrict__ cnt, float* __restrict__ dinv,
                            int n, int E) {
    __shared__ int s[256];
    int t = threadIdx.x;
    int b = blockIdx.x;
    s[t] = sums[t];
    __syncthreads();
    for (int off = 1; off < 256; off <<= 1) {
        int add = (t >= off) ? s[t - off] : 0;
        __syncthreads();
        s[t] += add;
        __syncthreads();
    }
    int prefix = (b == 0) ? 0 : s[b - 1];
    int i = b * 256 + t;
    if (i < n) {
        rowp[i] += prefix;
        dinv[i] = rsqrtf((float)cnt[i] + 1.0f);   // deg includes self-loop
    }
    if (i == 0) rowp[n] = E;
}

// ---- fused: gemm1 (blocks < GB) + atomic-free CSR fill (blocks >= GB) -----
// gemm: out = (A @ W) * dinv[:,None], bf16 MFMA, W staged to LDS.
// A read as f32 or bf16 per *flag (dual-dtype path, proven in round 6).

__global__ void k_gemm1_fill(const void* __restrict__ Av, const u16* __restrict__ W,
                             const float* __restrict__ dinv, u16* __restrict__ out,
                             int M, int GB, const int* __restrict__ flag,
                             const int* __restrict__ src, const int* __restrict__ dst,
                             const int* __restrict__ pos, const int* __restrict__ rowp,
                             int* __restrict__ col, int E) {
    constexpr int NOUT = 128;
    int t = threadIdx.x;
    if ((int)blockIdx.x >= GB) {
        // CSR fill: position precomputed, no atomics
        int stride = (gridDim.x - GB) * 256;
        for (int e = ((int)blockIdx.x - GB) * 256 + t; e < E; e += stride)
            col[rowp[dst[e]] + pos[e]] = src[e];
        return;
    }
    __shared__ u16 Wt[NOUT][136];
    for (int idx = t; idx < NOUT * 128; idx += 256) {
        int k = idx / NOUT, n = idx % NOUT;   // W row-major [128][NOUT]
        Wt[n][k] = W[idx];
    }
    __syncthreads();
    int wave = t >> 6, lane = t & 63;
    int m0 = ((int)blockIdx.x * 4 + wave) * 16;
    if (m0 >= M) return;
    int q = lane >> 4;
    int mr = lane & 15;

    short8 a[4];
    if (*flag) {
        const float* arow = (const float*)Av + (size_t)(m0 + mr) * 128 + q * 8;
#pragma unroll
        for (int c = 0; c < 4; c++) {
            f32x4 lo = *(const f32x4*)(arow + c * 32);
            f32x4 hi = *(const f32x4*)(arow + c * 32 + 4);
            a[c][0] = (short)f2bf(lo.x); a[c][1] = (short)f2bf(lo.y);
            a[c][2] = (short)f2bf(lo.z); a[c][3] = (short)f2bf(lo.w);
            a[c][4] = (short)f2bf(hi.x); a[c][5] = (short)f2bf(hi.y);
            a[c][6] = (short)f2bf(hi.z); a[c][7] = (short)f2bf(hi.w);
        }
    } else {
        const u16* arow = (const u16*)Av + (size_t)(m0 + mr) * 128 + q * 8;
#pragma unroll
        for (int c = 0; c < 4; c++) a[c] = *(const short8*)(arow + c * 32);
    }

    f32x4 acc[NOUT / 16];
#pragma unroll
    for (int tl = 0; tl < NOUT / 16; tl++) acc[tl] = (f32x4){0.f, 0.f, 0.f, 0.f};
#pragma unroll
    for (int c = 0; c < 4; c++) {
#pragma unroll
        for (int tl = 0; tl < NOUT / 16; tl++) {
            short8 b = *(const short8*)(&Wt[tl * 16 + mr][c * 32 + q * 8]);
            acc[tl] = __builtin_amdgcn_mfma_f32_16x16x32_bf16(a[c], b, acc[tl], 0, 0, 0);
        }
    }
    int rbase = m0 + q * 4;   // C/D: col=lane&15, row=(lane>>4)*4+reg
#pragma unroll
    for (int tl = 0; tl < NOUT / 16; tl++) {
#pragma unroll
        for (int r = 0; r < 4; r++) {
            int row = rbase + r;
            float v = acc[tl][r] * dinv[row];
            out[(size_t)row * NOUT + tl * 16 + mr] = f2bf(v);
        }
    }
}

// ---- plain GEMM (layer 2; A is always bf16 o1) ----------------------------

template <int NOUT>
__global__ void k_gemm_scale(const u16* __restrict__ A, const u16* __restrict__ W,
                             const float* __restrict__ dinv, u16* __restrict__ out, int M) {
    __shared__ u16 Wt[NOUT][136];
    int t = threadIdx.x;
    for (int idx = t; idx < NOUT * 128; idx += 256) {
        int k = idx / NOUT, n = idx % NOUT;
        Wt[n][k] = W[idx];
    }
    __syncthreads();
    int wave = t >> 6, lane = t & 63;
    int m0 = ((int)blockIdx.x * 4 + wave) * 16;
    if (m0 >= M) return;
    int q = lane >> 4;
    int mr = lane & 15;

    const u16* arow = A + (size_t)(m0 + mr) * 128 + q * 8;
    short8 a[4];
#pragma unroll
    for (int c = 0; c < 4; c++) a[c] = *(const short8*)(arow + c * 32);

    f32x4 acc[NOUT / 16];
#pragma unroll
    for (int tl = 0; tl < NOUT / 16; tl++) acc[tl] = (f32x4){0.f, 0.f, 0.f, 0.f};
#pragma unroll
    for (int c = 0; c < 4; c++) {
#pragma unroll
        for (int tl = 0; tl < NOUT / 16; tl++) {
            short8 b = *(const short8*)(&Wt[tl * 16 + mr][c * 32 + q * 8]);
            acc[tl] = __builtin_amdgcn_mfma_f32_16x16x32_bf16(a[c], b, acc[tl], 0, 0, 0);
        }
    }
    int rbase = m0 + q * 4;
#pragma unroll
    for (int tl = 0; tl < NOUT / 16; tl++) {
#pragma unroll
        for (int r = 0; r < 4; r++) {
            int row = rbase + r;
            float v = acc[tl][r] * dinv[row];
            out[(size_t)row * NOUT + tl * 16 + mr] = f2bf(v);
        }
    }
}

// ---- CSR gather aggregation (round-5/6 passing body) ----------------------
// One WAVE per node; wave-uniform control flow; 16B uint4 gathers.
// Output: f32 when *flag (harness output dtype), else bf16.

template <int F>
__global__ void k_agg(const u16* __restrict__ g, const int* __restrict__ rowp,
                      const int* __restrict__ col, const float* __restrict__ dinv,
                      const u16* __restrict__ bias, u16* __restrict__ outh,
                      float* __restrict__ outf, const int* __restrict__ flag,
                      int N, int E) {
    constexpr int LPR = F / 8;      // lanes covering one feature row
    constexpr int EPW = 64 / LPR;   // edges per wave load-instruction
    int d = blockIdx.x * 4 + (threadIdx.x >> 6);
    if (d >= N) return;             // wave-uniform exit
    int lane = threadIdx.x & 63;
    int er = lane / LPR;
    int fo = (lane % LPR) * 8;

    int beg = rowp[d], end = rowp[d + 1];
    if (beg < 0) beg = 0;
    if (end > E) end = E;
    int deg = end - beg;

    float a0[8], a1[8];
#pragma unroll
    for (int j = 0; j < 8; j++) { a0[j] = 0.f; a1[j] = 0.f; }

    for (int base = 0; base < deg; base += 64) {   // deg uniform across wave
        int cnt = deg - base; if (cnt > 64) cnt = 64;
        int colv = 0;
        if (lane < cnt) {                          // predicated load only
            int s = col[beg + base + lane];
            colv = s < 0 ? 0 : (s >= N ? N - 1 : s);
        }
        int full = cnt / EPW;                      // uniform trip count
        int i = 0;
        for (; i + 2 <= full; i += 2) {
            int s0 = __shfl(colv, i * EPW + er, 64);
            int s1 = __shfl(colv, (i + 1) * EPW + er, 64);
            uint4 v0 = *(const uint4*)(g + (size_t)s0 * F + fo);
            uint4 v1 = *(const uint4*)(g + (size_t)s1 * F + fo);
            a0[0] += bflo(v0.x); a0[1] += bfhi(v0.x);
            a0[2] += bflo(v0.y); a0[3] += bfhi(v0.y);
            a0[4] += bflo(v0.z); a0[5] += bfhi(v0.z);
            a0[6] += bflo(v0.w); a0[7] += bfhi(v0.w);
            a1[0] += bflo(v1.x); a1[1] += bfhi(v1.x);
            a1[2] += bflo(v1.y); a1[3] += bfhi(v1.y);
            a1[4] += bflo(v1.z); a1[5] += bfhi(v1.z);
            a1[6] += bflo(v1.w); a1[7] += bfhi(v1.w);
        }
        if (i < full) {
            int s0 = __shfl(colv, i * EPW + er, 64);
            uint4 v0 = *(const uint4*)(g + (size_t)s0 * F + fo);
            a0[0] += bflo(v0.x); a0[1] += bfhi(v0.x);
            a0[2] += bflo(v0.y); a0[3] += bfhi(v0.y);
            a0[4] += bflo(v0.z); a0[5] += bfhi(v0.z);
            a0[6] += bflo(v0.w); a0[7] += bfhi(v0.w);
            i++;
        }
        int rem = cnt - full * EPW;                // leftover edges
        int s0 = __shfl(colv, (full * EPW + er) & 63, 64);   // uniform shfl
        if (er < rem) {                            // predicated load only
            uint4 v0 = *(const uint4*)(g + (size_t)s0 * F + fo);
            a0[0] += bflo(v0.x); a0[1] += bfhi(v0.x);
            a0[2] += bflo(v0.y); a0[3] += bfhi(v0.y);
            a0[4] += bflo(v0.z); a0[5] += bfhi(v0.z);
            a0[6] += bflo(v0.w); a0[7] += bfhi(v0.w);
        }
    }
#pragma unroll
    for (int j = 0; j < 8; j++) a0[j] += a1[j];
    // butterfly: sum across edge groups (all 64 lanes active, uniform)
#pragma unroll
    for (int off = LPR; off < 64; off <<= 1) {
#pragma unroll
        for (int j = 0; j < 8; j++) a0[j] += __shfl_xor(a0[j], off, 64);
    }

    if (lane < LPR) {   // er == 0 lanes own the result
        uint4 sv = *(const uint4*)(g + (size_t)d * F + fo);
        uint4 bv = *(const uint4*)(bias + fo);
        float di = dinv[d];
        float r[8];
        r[0] = di * (a0[0] + bflo(sv.x)) + bflo(bv.x);
        r[1] = di * (a0[1] + bfhi(sv.x)) + bfhi(bv.x);
        r[2] = di * (a0[2] + bflo(sv.y)) + bflo(bv.y);
        r[3] = di * (a0[3] + bfhi(sv.y)) + bfhi(bv.y);
        r[4] = di * (a0[4] + bflo(sv.z)) + bflo(bv.z);
        r[5] = di * (a0[5] + bfhi(sv.z)) + bfhi(bv.z);
        r[6] = di * (a0[6] + bflo(sv.w)) + bflo(bv.w);
        r[7] = di * (a0[7] + bfhi(sv.w)) + bfhi(bv.w);
#pragma unroll
        for (int j = 0; j < 8; j++) r[j] = r[j] > 0.f ? r[j] : 0.f;
        size_t o = (size_t)d * F + fo;
        if (flag && *flag) {
            f32x4 w0 = {r[0], r[1], r[2], r[3]};
            f32x4 w1 = {r[4], r[5], r[6], r[7]};
            *(f32x4*)(outf + o) = w0;
            *(f32x4*)(outf + o + 4) = w1;
        } else {
            uint4 w;
            w.x = (unsigned)f2bf(r[0]) | ((unsigned)f2bf(r[1]) << 16);
            w.y = (unsigned)f2bf(r[2]) | ((unsigned)f2bf(r[3]) << 16);
            w.z = (unsigned)f2bf(r[4]) | ((unsigned)f2bf(r[5]) << 16);
            w.w = (unsigned)f2bf(r[6]) | ((unsigned)f2bf(r[7]) << 16);
            *(uint4*)(outh + o) = w;
        }
    }
}

// ---- launch ---------------------------------------------------------------

extern "C" void kernel_launch(void* const* d_in, const int* in_sizes, int n_in,
                              void* d_out, int out_size, void* d_ws, size_t ws_size,
                              hipStream_t stream) {
    const int N = in_sizes[0] / 128;
    const int E = in_sizes[1] / 2;
    const int* ei = (const int*)d_in[1];
    const int* src = ei;
    const int* dst = ei + E;

    char* p = (char*)d_ws;
    auto alloc = [&](size_t b) { char* r = p; p += (b + 255) & ~(size_t)255; return r; };
    int*   flag = (int*)alloc(256);
    int*   rowp = (int*)alloc((size_t)(N + 1) * 4);
    float* dinv = (float*)alloc((size_t)N * 4);
    int*   col  = (int*)alloc((size_t)E * 4);
    u16*   wbuf = (u16*)alloc((size_t)(128 * 128 + 128 + 128 * 64 + 64) * 2);
    char*  slotA = alloc((size_t)N * 128 * 2);   // cnt+sums early; g1; g2
    char*  slotB = alloc((size_t)N * 128 * 2);   // pos early; o1 later

    int* cnt  = (int*)slotA;                     // dead after k_finalize2
    int* sums = (int*)(slotA + (size_t)N * 4);   // dead after k_finalize2
    u16* g1   = (u16*)slotA;                     // written by gemm1
    u16* g2   = (u16*)slotA;                     // written by gemm2
    int* pos  = (int*)slotB;                     // dead after fill
    u16* o1   = (u16*)slotB;                     // written by agg1
    u16* W1C = wbuf;
    u16* b1C = wbuf + 128 * 128;
    u16* W2C = b1C + 128;
    u16* b2C = W2C + 128 * 64;

    // 1. dtype detect + weight canonicalization (inputs are f32 in practice)
    k_detect<<<1, 256, 0, stream>>>((const u16*)d_in[0], flag);
    k_convert_w<<<97, 256, 0, stream>>>(d_in[2], d_in[3], d_in[4], d_in[5], wbuf, flag);

    // 2. CSR build
    hipMemsetAsync(slotA, 0, (size_t)N * 4 + 1024, stream);   // cnt + sums
    int eb = (E + 255) / 256;
    int nb = (N + 255) / 256;
    k_degpos<<<eb, 256, 0, stream>>>(dst, cnt, pos, E);
    k_scan_blocks<<<nb, 256, 0, stream>>>(cnt, rowp, sums, N);
    k_finalize2<<<nb, 256, 0, stream>>>(rowp, sums, cnt, dinv, N, E);

    // 3. fused gemm1 (dual-dtype x) + atomic-free CSR fill
    int GB = (N / 16 + 3) / 4;
    int FB = GB;
    k_gemm1_fill<<<GB + FB, 256, 0, stream>>>(d_in[0], W1C, dinv, g1, N, GB, flag,
                                              src, dst, pos, rowp, col, E);

    // 4. aggregate L1 -> o1 (bf16); gemm2 (bf16); aggregate L2 -> out (f32/bf16)
    int ab = (N + 3) / 4;   // one wave per node, 4 waves/block
    k_agg<128><<<ab, 256, 0, stream>>>(g1, rowp, col, dinv, b1C,
                                       o1, nullptr, nullptr, N, E);
    k_gemm_scale<64><<<GB, 256, 0, stream>>>(o1, W2C, dinv, g2, N);
    k_agg<64><<<ab, 256, 0, stream>>>(g2, rowp, col, dinv, b2C,
                                      (u16*)d_out, (float*)d_out, flag, N, E);
}